// Round 3
// baseline (434.150 us; speedup 1.0000x reference)
//
#include <hip/hip_runtime.h>

#define SLOPE 0.01f

// 5-layer 8->8 MLP, leaky ReLU after first 4 layers.
// w: 5*64 fp32, row-major w[L][j][k] (out[j] += w[L][j*8+k] * x[k]); b: 5*8.
__device__ __forceinline__ void mlp8(const float* __restrict__ w,
                                     const float* __restrict__ b,
                                     const float x[8], float out[8]) {
    float a[8];
    #pragma unroll
    for (int j = 0; j < 8; ++j) a[j] = x[j];
    #pragma unroll
    for (int L = 0; L < 5; ++L) {
        const float* wl = w + L * 64;
        const float* bl = b + L * 8;
        float t[8];
        #pragma unroll
        for (int j = 0; j < 8; ++j) {
            float acc = bl[j];
            #pragma unroll
            for (int k = 0; k < 8; ++k)
                acc = fmaf(wl[j * 8 + k], a[k], acc);
            t[j] = acc;
        }
        #pragma unroll
        for (int j = 0; j < 8; ++j)
            a[j] = (L < 4) ? fmaxf(t[j], SLOPE * t[j]) : t[j];
    }
    #pragma unroll
    for (int j = 0; j < 8; ++j) out[j] = a[j];
}

__global__ void __launch_bounds__(256)
coupling_kernel(const float4* __restrict__ z,   // 4 x float4 per row (16 fp32)
                const float* __restrict__ wl,   // ws_logs: 5*64 fp32
                const float* __restrict__ bl,   // bs_logs: 5*8
                const float* __restrict__ wv,   // ws_b:    5*64
                const float* __restrict__ bv,   // bs_b:    5*8
                float4* __restrict__ out,
                int batch) {
    int idx = blockIdx.x * blockDim.x + threadIdx.x;
    if (idx >= batch) return;

    size_t base = (size_t)idx * 4;
    float4 r0 = z[base + 0];   // zl[0..3]
    float4 r1 = z[base + 1];   // zl[4..7]
    float4 r2 = z[base + 2];   // zr[0..3]
    float4 r3 = z[base + 3];   // zr[4..7]

    float zl[8] = { r0.x, r0.y, r0.z, r0.w, r1.x, r1.y, r1.z, r1.w };
    float zr[8] = { r2.x, r2.y, r2.z, r2.w, r3.x, r3.y, r3.z, r3.w };

    float log_s[8], bb[8];
    mlp8(wl, bl, zl, log_s);
    mlp8(wv, bv, zl, bb);

    float yr[8];
    #pragma unroll
    for (int k = 0; k < 8; ++k)
        yr[k] = fmaf(__expf(log_s[k]), zr[k], bb[k]);

    out[base + 0] = r0;                                        // zl pass-through (bit-exact)
    out[base + 1] = r1;
    out[base + 2] = make_float4(yr[0], yr[1], yr[2], yr[3]);
    out[base + 3] = make_float4(yr[4], yr[5], yr[6], yr[7]);
}

extern "C" void kernel_launch(void* const* d_in, const int* in_sizes, int n_in,
                              void* d_out, int out_size, void* d_ws, size_t ws_size,
                              hipStream_t stream) {
    const int batch = in_sizes[0] / 16;

    const float *wl, *bl, *wv, *bv;
    if (n_in >= 21) {
        // Defensive path: lists flattened into 20 separate arrays — stage into
        // contiguous fp32 blocks in d_ws via D2D memcpy (graph-capture legal).
        float* ws = (float*)d_ws;   // [0,320) wl, [320,360) bl, [360,680) wv, [680,720) bv
        for (int i = 0; i < 5; ++i) {
            hipMemcpyAsync(ws + i * 64,        d_in[1 + i],  64 * 4, hipMemcpyDeviceToDevice, stream);
            hipMemcpyAsync(ws + 320 + i * 8,   d_in[6 + i],   8 * 4, hipMemcpyDeviceToDevice, stream);
            hipMemcpyAsync(ws + 360 + i * 64,  d_in[11 + i], 64 * 4, hipMemcpyDeviceToDevice, stream);
            hipMemcpyAsync(ws + 680 + i * 8,   d_in[16 + i],  8 * 4, hipMemcpyDeviceToDevice, stream);
        }
        wl = ws; bl = ws + 320; wv = ws + 360; bv = ws + 680;
    } else {
        // Expected path (n_in == 5): each list passed as one concatenated array.
        wl = (const float*)d_in[1];   // ws_logs: 5 x (8x8)
        bl = (const float*)d_in[2];   // bs_logs: 5 x 8
        wv = (const float*)d_in[3];   // ws_b:    5 x (8x8)
        bv = (const float*)d_in[4];   // bs_b:    5 x 8
    }

    int threads = 256;
    int blocks = (batch + threads - 1) / threads;
    coupling_kernel<<<blocks, threads, 0, stream>>>(
        (const float4*)d_in[0], wl, bl, wv, bv, (float4*)d_out, batch);
}